// Round 2
// baseline (357.117 us; speedup 1.0000x reference)
//
#include <hip/hip_runtime.h>
#include <hip/hip_bf16.h>

// Residual_Comb_Conv: B=2048, C_IN=64, C_MID=64, C_OUT=128, R=60, K=13
// Per-batch fused bf16 MFMA GEMMs.
//   z = relu(bn(x)) precomputed per batch (gather commutes with elementwise).
//   z column-major in LDS (64 ch contiguous per r', 144 B stride): gathered
//   B-fragment = one ds_read_b128 per lane.
//   R2 changes vs R1:
//     - nei byte-offsets prefetched into registers one iteration ahead
//       (removes the dependent ds_read_b32 -> ds_read_b128 chain).
//     - re-tiled: stage1 2m x 2n per wave, stage2 4m x 2n per wave
//       (B-fragment LDS reads per MFMA halved; waves pair up on A rows).
//     - prep_w coalesced (thread per (o,c), contiguous 13-float reads).

typedef __attribute__((ext_vector_type(8))) short bf16x8;
typedef __attribute__((ext_vector_type(4))) float f32x4;
typedef __attribute__((ext_vector_type(4))) unsigned short us4;

#define EPSV 1e-5f
#define ZSTRIDE 72            // elements per z column: 64 ch + 8 pad (144 B)
#define ZCOLBYTES 144
#define ZELEMS (64 * ZSTRIDE) // 4608 elements per z buffer

__device__ __forceinline__ unsigned short f2bf(float f) {
  unsigned int u = __builtin_bit_cast(unsigned int, f);
  u += 0x7FFFu + ((u >> 16) & 1u);   // round-to-nearest-even
  return (unsigned short)(u >> 16);
}

// ---- prep: W1 [64][64][13] -> W1t bf16 [64][13*64] (kk = ks*64 + c)
//           W2|W3 [128][64][13] -> W23t bf16 [128][26*64] (f-source then x-source)
// One thread per (o,c): reads 13 contiguous floats, writes per-ks coalesced bf16.
__global__ void prep_w(const float* __restrict__ W1, const float* __restrict__ W2,
                       const float* __restrict__ W3, unsigned short* __restrict__ W1t,
                       unsigned short* __restrict__ W23t) {
  int t = blockIdx.x * 256 + threadIdx.x;
  if (t < 4096) {                        // W1: 64*64 rows
    int o = t >> 6, c = t & 63;
    const float* src = W1 + (o * 64 + c) * 13;
    unsigned short* dst = W1t + o * 832 + c;
    #pragma unroll
    for (int ks = 0; ks < 13; ks++) dst[ks * 64] = f2bf(src[ks]);
  } else if (t < 20480) {                // W2,W3: 2*128*64 rows
    int idx = t - 4096;
    int half = idx >> 13;                // 0 -> W2, 1 -> W3
    int o = (idx >> 6) & 127, c = idx & 63;
    const float* src = (half ? W3 : W2) + (o * 64 + c) * 13;
    unsigned short* dst = W23t + o * 1664 + half * 13 * 64 + c;
    #pragma unroll
    for (int ks = 0; ks < 13; ks++) dst[ks * 64] = f2bf(src[ks]);
  }
}

#define MFMA __builtin_amdgcn_mfma_f32_16x16x32_bf16

__global__ __launch_bounds__(256, 3) void fused_k(
    const float* __restrict__ x, const int* __restrict__ nei,
    const float* __restrict__ g1, const float* __restrict__ be1,
    const float* __restrict__ mu1, const float* __restrict__ va1,
    const float* __restrict__ c1,
    const float* __restrict__ g2, const float* __restrict__ be2,
    const float* __restrict__ mu2, const float* __restrict__ va2,
    const float* __restrict__ c2,
    const float* __restrict__ g3, const float* __restrict__ be3,
    const float* __restrict__ mu3, const float* __restrict__ va3,
    const float* __restrict__ c3,
    const unsigned short* __restrict__ W1t,
    const unsigned short* __restrict__ W23t,
    float* __restrict__ out)
{
  __shared__ unsigned short z1[ZELEMS];      // act1(x), column-major [r'][c]
  __shared__ unsigned short zz[2 * ZELEMS];  // z2 = act2(f) | z3 = act3(x)
  __shared__ int lneio[780];                 // nei[r*13+k] * 144 (byte offset)
  __shared__ float pp[6 * 64];               // a1,b1',a2,b2',a3,b3'
  __shared__ float pcc[128];                 // c2 + c3

  const int tid  = threadIdx.x;
  const int wave = tid >> 6;
  const int lane = tid & 63;
  const int quad = lane >> 4;
  const int nl   = lane & 15;

  // ---- fold BN params
  if (tid < 64) {
    float a1v = g1[tid] * rsqrtf(va1[tid] + EPSV);
    pp[tid]       = a1v;
    pp[64 + tid]  = be1[tid] - mu1[tid] * a1v;
    float a2v = g2[tid] * rsqrtf(va2[tid] + EPSV);
    pp[128 + tid] = a2v;
    pp[192 + tid] = be2[tid] - mu2[tid] * a2v + a2v * c1[tid]; // fold conv1 bias
    float a3v = g3[tid] * rsqrtf(va3[tid] + EPSV);
    pp[256 + tid] = a3v;
    pp[320 + tid] = be3[tid] - mu3[tid] * a3v;
  } else if (tid >= 128) {
    pcc[tid - 128] = c2[tid - 128] + c3[tid - 128];
  }
  for (int i = tid; i < 780; i += 256) lneio[i] = nei[i] * ZCOLBYTES;
  __syncthreads();

  // ---- build z1 = act1(x), z3 = act3(x)
  const float* xb = x + blockIdx.x * (64 * 60);
  unsigned short* z3p = zz + ZELEMS;
  for (int i = tid; i < 64 * 60; i += 256) {
    int c = i / 60;
    int r = i - c * 60;
    float xv = xb[i];
    z1[r * ZSTRIDE + c]  = f2bf(fmaxf(fmaf(xv, pp[c],       pp[64 + c]),  0.f));
    z3p[r * ZSTRIDE + c] = f2bf(fmaxf(fmaf(xv, pp[256 + c], pp[320 + c]), 0.f));
  }
  __syncthreads();

  // wave tiling: npair = wave&1 selects n-tiles {npair*2, npair*2+1}
  const int r0 = (wave & 1) * 32 + nl;
  const int r1 = r0 + 16;
  const int r0c13 = (r0 < 60 ? r0 : 59) * 13;   // clamp pad cols; masked at store
  const int r1c13 = (r1 < 60 ? r1 : 59) * 13;

  // ---- stage 1: F[64x64] = W1t[64x832] . H1(z1); wave = 2m x 2n
  f32x4 acc1[4] = {};   // [mt*2+nt]
  {
    const unsigned short* wpa = W1t + ((wave >> 1) * 32 + nl) * 832 + quad * 8;
    const unsigned short* wpb = wpa + 16 * 832;
    bf16x8 a0c0 = *(const bf16x8*)(wpa);
    bf16x8 a0c1 = *(const bf16x8*)(wpa + 32);
    bf16x8 a1c0 = *(const bf16x8*)(wpb);
    bf16x8 a1c1 = *(const bf16x8*)(wpb + 32);
    const char* zb = (const char*)z1 + quad * 16;
    int no0 = lneio[r0c13];
    int no1 = lneio[r1c13];
    #pragma unroll 1
    for (int ks = 0; ks < 13; ks++) {
      int ksn = (ks < 12) ? ks + 1 : 12;
      int non0 = lneio[r0c13 + ksn];          // offsets for NEXT iter
      int non1 = lneio[r1c13 + ksn];
      int pf = ksn * 64;
      bf16x8 n0c0 = *(const bf16x8*)(wpa + pf);
      bf16x8 n0c1 = *(const bf16x8*)(wpa + pf + 32);
      bf16x8 n1c0 = *(const bf16x8*)(wpb + pf);
      bf16x8 n1c1 = *(const bf16x8*)(wpb + pf + 32);
      bf16x8 b;
      b = *(const bf16x8*)(zb + no0);
      acc1[0] = MFMA(a0c0, b, acc1[0], 0, 0, 0);
      acc1[2] = MFMA(a1c0, b, acc1[2], 0, 0, 0);
      b = *(const bf16x8*)(zb + no0 + 64);
      acc1[0] = MFMA(a0c1, b, acc1[0], 0, 0, 0);
      acc1[2] = MFMA(a1c1, b, acc1[2], 0, 0, 0);
      b = *(const bf16x8*)(zb + no1);
      acc1[1] = MFMA(a0c0, b, acc1[1], 0, 0, 0);
      acc1[3] = MFMA(a1c0, b, acc1[3], 0, 0, 0);
      b = *(const bf16x8*)(zb + no1 + 64);
      acc1[1] = MFMA(a0c1, b, acc1[1], 0, 0, 0);
      acc1[3] = MFMA(a1c1, b, acc1[3], 0, 0, 0);
      a0c0 = n0c0; a0c1 = n0c1; a1c0 = n1c0; a1c1 = n1c1;
      no0 = non0; no1 = non1;
    }
  }

  // ---- act2(F) -> z2 (D layout: row o = quad*4+reg, col r = nl-based)
  {
    #pragma unroll
    for (int mt = 0; mt < 2; mt++) {
      int ob = (wave >> 1) * 32 + mt * 16 + quad * 4;
      float a20 = pp[128 + ob],     a21 = pp[128 + ob + 1];
      float a22 = pp[128 + ob + 2], a23 = pp[128 + ob + 3];
      float b20 = pp[192 + ob],     b21 = pp[192 + ob + 1];
      float b22 = pp[192 + ob + 2], b23 = pp[192 + ob + 3];
      #pragma unroll
      for (int nt = 0; nt < 2; nt++) {
        int r = (wave & 1) * 32 + nt * 16 + nl;   // <=63, in-bounds; cols>=60 never read
        f32x4 a = acc1[mt * 2 + nt];
        us4 w;
        w.x = f2bf(fmaxf(fmaf(a[0], a20, b20), 0.f));
        w.y = f2bf(fmaxf(fmaf(a[1], a21, b21), 0.f));
        w.z = f2bf(fmaxf(fmaf(a[2], a22, b22), 0.f));
        w.w = f2bf(fmaxf(fmaf(a[3], a23, b23), 0.f));
        *(us4*)&zz[r * ZSTRIDE + ob] = w;
      }
    }
  }
  __syncthreads();

  // ---- stage 2: OUT[128x64] = W23t[128x1664] . [H2(z2); H3(z3)]; wave = 4m x 2n
  f32x4 acc2[8] = {};   // [mt*2+nt]
  {
    const unsigned short* wp0 = W23t + ((wave >> 1) * 64 + nl) * 1664 + quad * 8;
    const unsigned short* wp1 = wp0 + 16 * 1664;
    const unsigned short* wp2 = wp0 + 32 * 1664;
    const unsigned short* wp3 = wp0 + 48 * 1664;
    bf16x8 a0c0 = *(const bf16x8*)(wp0), a0c1 = *(const bf16x8*)(wp0 + 32);
    bf16x8 a1c0 = *(const bf16x8*)(wp1), a1c1 = *(const bf16x8*)(wp1 + 32);
    bf16x8 a2c0 = *(const bf16x8*)(wp2), a2c1 = *(const bf16x8*)(wp2 + 32);
    bf16x8 a3c0 = *(const bf16x8*)(wp3), a3c1 = *(const bf16x8*)(wp3 + 32);
    const char* zzb = (const char*)zz + quad * 16;
    int no0 = lneio[r0c13];
    int no1 = lneio[r1c13];
    #pragma unroll 1
    for (int kt = 0; kt < 26; kt++) {          // kt = src*13 + ks
      int ktn = (kt < 25) ? kt + 1 : 25;
      int ksn = (ktn < 13) ? ktn : ktn - 13;
      int non0 = lneio[r0c13 + ksn];           // offsets for NEXT iter
      int non1 = lneio[r1c13 + ksn];
      int pf = ktn * 64;
      bf16x8 n0c0 = *(const bf16x8*)(wp0 + pf), n0c1 = *(const bf16x8*)(wp0 + pf + 32);
      bf16x8 n1c0 = *(const bf16x8*)(wp1 + pf), n1c1 = *(const bf16x8*)(wp1 + pf + 32);
      bf16x8 n2c0 = *(const bf16x8*)(wp2 + pf), n2c1 = *(const bf16x8*)(wp2 + pf + 32);
      bf16x8 n3c0 = *(const bf16x8*)(wp3 + pf), n3c1 = *(const bf16x8*)(wp3 + pf + 32);
      const char* zb = zzb + ((kt < 13) ? 0 : 2 * ZELEMS);  // bytes: z2 | z3
      bf16x8 b;
      b = *(const bf16x8*)(zb + no0);
      acc2[0] = MFMA(a0c0, b, acc2[0], 0, 0, 0);
      acc2[2] = MFMA(a1c0, b, acc2[2], 0, 0, 0);
      acc2[4] = MFMA(a2c0, b, acc2[4], 0, 0, 0);
      acc2[6] = MFMA(a3c0, b, acc2[6], 0, 0, 0);
      b = *(const bf16x8*)(zb + no0 + 64);
      acc2[0] = MFMA(a0c1, b, acc2[0], 0, 0, 0);
      acc2[2] = MFMA(a1c1, b, acc2[2], 0, 0, 0);
      acc2[4] = MFMA(a2c1, b, acc2[4], 0, 0, 0);
      acc2[6] = MFMA(a3c1, b, acc2[6], 0, 0, 0);
      b = *(const bf16x8*)(zb + no1);
      acc2[1] = MFMA(a0c0, b, acc2[1], 0, 0, 0);
      acc2[3] = MFMA(a1c0, b, acc2[3], 0, 0, 0);
      acc2[5] = MFMA(a2c0, b, acc2[5], 0, 0, 0);
      acc2[7] = MFMA(a3c0, b, acc2[7], 0, 0, 0);
      b = *(const bf16x8*)(zb + no1 + 64);
      acc2[1] = MFMA(a0c1, b, acc2[1], 0, 0, 0);
      acc2[3] = MFMA(a1c1, b, acc2[3], 0, 0, 0);
      acc2[5] = MFMA(a2c1, b, acc2[5], 0, 0, 0);
      acc2[7] = MFMA(a3c1, b, acc2[7], 0, 0, 0);
      a0c0 = n0c0; a0c1 = n0c1; a1c0 = n1c0; a1c1 = n1c1;
      a2c0 = n2c0; a2c1 = n2c1; a3c0 = n3c0; a3c1 = n3c1;
      no0 = non0; no1 = non1;
    }
  }

  // ---- epilogue: out[b][o][r] = acc2 + (c2[o] + c3[o])
  float* outb = out + blockIdx.x * (128 * 60);
  #pragma unroll
  for (int mt = 0; mt < 4; mt++) {
    int ob = (wave >> 1) * 64 + mt * 16 + quad * 4;
    float q0 = pcc[ob], q1 = pcc[ob + 1], q2 = pcc[ob + 2], q3 = pcc[ob + 3];
    #pragma unroll
    for (int nt = 0; nt < 2; nt++) {
      int r = (wave & 1) * 32 + nt * 16 + nl;
      if (r < 60) {
        f32x4 a = acc2[mt * 2 + nt];
        outb[(ob + 0) * 60 + r] = a[0] + q0;
        outb[(ob + 1) * 60 + r] = a[1] + q1;
        outb[(ob + 2) * 60 + r] = a[2] + q2;
        outb[(ob + 3) * 60 + r] = a[3] + q3;
      }
    }
  }
}

extern "C" void kernel_launch(void* const* d_in, const int* in_sizes, int n_in,
                              void* d_out, int out_size, void* d_ws, size_t ws_size,
                              hipStream_t stream) {
  const float* x   = (const float*)d_in[0];
  const int*   nei = (const int*)d_in[1];
  const float* g1  = (const float*)d_in[2];
  const float* be1 = (const float*)d_in[3];
  const float* mu1 = (const float*)d_in[4];
  const float* va1 = (const float*)d_in[5];
  const float* W1  = (const float*)d_in[6];
  const float* c1  = (const float*)d_in[7];
  const float* g2  = (const float*)d_in[8];
  const float* be2 = (const float*)d_in[9];
  const float* mu2 = (const float*)d_in[10];
  const float* va2 = (const float*)d_in[11];
  const float* W2  = (const float*)d_in[12];
  const float* c2  = (const float*)d_in[13];
  const float* g3  = (const float*)d_in[14];
  const float* be3 = (const float*)d_in[15];
  const float* mu3 = (const float*)d_in[16];
  const float* va3 = (const float*)d_in[17];
  const float* W3  = (const float*)d_in[18];
  const float* c3  = (const float*)d_in[19];

  // workspace: W1t bf16 [64*832] then W23t bf16 [128*1664]  (~532 KB)
  unsigned short* W1t  = (unsigned short*)d_ws;
  unsigned short* W23t = W1t + 64 * 832;

  prep_w<<<80, 256, 0, stream>>>(W1, W2, W3, W1t, W23t);
  fused_k<<<2048, 256, 0, stream>>>(x, nei, g1, be1, mu1, va1, c1,
                                    g2, be2, mu2, va2, c2,
                                    g3, be3, mu3, va3, c3,
                                    W1t, W23t, (float*)d_out);
}

// Round 3
// 317.937 us; speedup vs baseline: 1.1232x; 1.1232x over previous
//
#include <hip/hip_runtime.h>
#include <hip/hip_bf16.h>

// Residual_Comb_Conv: B=2048, C_IN=64, C_MID=64, C_OUT=128, R=60, K=13
// R3: 2 batches per block (grid 1024) to halve per-CU weight-stream traffic
//     (theory: R1/R2 were L1/L2 A-fetch bound: 532 KB weights re-streamed per
//     block; R2's A-doubling cost exactly the predicted ~95 us).
//     Waves = (batch, m-half); batch-pair waves read identical A addresses
//     (L1 dedup). Per-wave tiles: stage1 2m x 4n, stage2 4m x 4n.
//     LDS reuse: z2 overwrites z1 after stage1 barrier; z3 built in prologue.

typedef __attribute__((ext_vector_type(8))) short bf16x8;
typedef __attribute__((ext_vector_type(4))) float f32x4;
typedef __attribute__((ext_vector_type(4))) unsigned short us4;

#define EPSV 1e-5f
#define ZSTRIDE 72            // shorts per z column: 64 ch + 8 pad (144 B)
#define ZCOLBYTES 144
#define ZELEMS (64 * ZSTRIDE) // 4608 shorts = 9216 B per z buffer

__device__ __forceinline__ unsigned short f2bf(float f) {
  unsigned int u = __builtin_bit_cast(unsigned int, f);
  u += 0x7FFFu + ((u >> 16) & 1u);   // round-to-nearest-even
  return (unsigned short)(u >> 16);
}

// ---- prep: W1 [64][64][13] -> W1t bf16 [64][13*64] (kk = ks*64 + c)
//           W2|W3 [128][64][13] -> W23t bf16 [128][26*64] (f-source | x-source)
__global__ void prep_w(const float* __restrict__ W1, const float* __restrict__ W2,
                       const float* __restrict__ W3, unsigned short* __restrict__ W1t,
                       unsigned short* __restrict__ W23t) {
  int t = blockIdx.x * 256 + threadIdx.x;
  if (t < 4096) {                        // W1: 64*64 rows
    int o = t >> 6, c = t & 63;
    const float* src = W1 + (o * 64 + c) * 13;
    unsigned short* dst = W1t + o * 832 + c;
    #pragma unroll
    for (int ks = 0; ks < 13; ks++) dst[ks * 64] = f2bf(src[ks]);
  } else if (t < 20480) {                // W2,W3: 2*128*64 rows
    int idx = t - 4096;
    int half = idx >> 13;                // 0 -> W2, 1 -> W3
    int o = (idx >> 6) & 127, c = idx & 63;
    const float* src = (half ? W3 : W2) + (o * 64 + c) * 13;
    unsigned short* dst = W23t + o * 1664 + half * 13 * 64 + c;
    #pragma unroll
    for (int ks = 0; ks < 13; ks++) dst[ks * 64] = f2bf(src[ks]);
  }
}

#define MFMA __builtin_amdgcn_mfma_f32_16x16x32_bf16

__global__ __launch_bounds__(256, 3) void fused_k(
    const float* __restrict__ x, const int* __restrict__ nei,
    const float* __restrict__ g1, const float* __restrict__ be1,
    const float* __restrict__ mu1, const float* __restrict__ va1,
    const float* __restrict__ c1,
    const float* __restrict__ g2, const float* __restrict__ be2,
    const float* __restrict__ mu2, const float* __restrict__ va2,
    const float* __restrict__ c2,
    const float* __restrict__ g3, const float* __restrict__ be3,
    const float* __restrict__ mu3, const float* __restrict__ va3,
    const float* __restrict__ c3,
    const unsigned short* __restrict__ W1t,
    const unsigned short* __restrict__ W23t,
    float* __restrict__ out)
{
  // zbuf[b]   : z1 (stage1) then overwritten by z2 (stage2), batch b
  // zbuf[2+b] : z3, batch b
  __shared__ unsigned short zbuf[4][ZELEMS];
  __shared__ int lneio[780];                 // nei[r*13+k] * 144 (byte offset)
  __shared__ float pp[6 * 64];               // a1,b1',a2,b2',a3,b3'
  __shared__ float pcc[128];                 // c2 + c3

  const int tid  = threadIdx.x;
  const int wave = tid >> 6;
  const int lane = tid & 63;
  const int quad = lane >> 4;
  const int nl   = lane & 15;
  const int bb   = wave & 1;    // batch within the pair
  const int mh   = wave >> 1;   // m-half

  // ---- fold BN params
  if (tid < 64) {
    float a1v = g1[tid] * rsqrtf(va1[tid] + EPSV);
    pp[tid]       = a1v;
    pp[64 + tid]  = be1[tid] - mu1[tid] * a1v;
    float a2v = g2[tid] * rsqrtf(va2[tid] + EPSV);
    pp[128 + tid] = a2v;
    pp[192 + tid] = be2[tid] - mu2[tid] * a2v + a2v * c1[tid]; // fold conv1 bias
    float a3v = g3[tid] * rsqrtf(va3[tid] + EPSV);
    pp[256 + tid] = a3v;
    pp[320 + tid] = be3[tid] - mu3[tid] * a3v;
  } else if (tid >= 128) {
    pcc[tid - 128] = c2[tid - 128] + c3[tid - 128];
  }
  for (int i = tid; i < 780; i += 256) lneio[i] = nei[i] * ZCOLBYTES;
  __syncthreads();

  // ---- build z1 = act1(x), z3 = act3(x) for both batches
  const int batch0 = blockIdx.x * 2;
  const float* xb = x + batch0 * 3840;
  for (int i = tid; i < 7680; i += 256) {
    int b = (i >= 3840);
    int j = i - b * 3840;
    int c = j / 60;
    int r = j - c * 60;
    float xv = xb[b * 3840 + j];
    zbuf[b][r * ZSTRIDE + c]     = f2bf(fmaxf(fmaf(xv, pp[c],       pp[64 + c]),  0.f));
    zbuf[2 + b][r * ZSTRIDE + c] = f2bf(fmaxf(fmaf(xv, pp[256 + c], pp[320 + c]), 0.f));
  }
  __syncthreads();

  int rc13[4];
  #pragma unroll
  for (int nt = 0; nt < 4; nt++) {
    int r = nt * 16 + nl;
    rc13[nt] = (r < 60 ? r : 59) * 13;   // clamp pad cols; masked at store
  }

  // ---- stage 1: F[64x64] = W1t[64x832] . H1(z1[bb]); wave = 2m x 4n
  f32x4 acc1[8] = {};   // [mt*4+nt]
  {
    const unsigned short* wA = W1t + (mh * 32 + nl) * 832 + quad * 8;
    bf16x8 a00 = *(const bf16x8*)(wA);
    bf16x8 a01 = *(const bf16x8*)(wA + 32);
    bf16x8 a10 = *(const bf16x8*)(wA + 16 * 832);
    bf16x8 a11 = *(const bf16x8*)(wA + 16 * 832 + 32);
    const char* zb = (const char*)zbuf[bb] + quad * 16;
    int no0 = lneio[rc13[0]], no1 = lneio[rc13[1]];
    int no2 = lneio[rc13[2]], no3 = lneio[rc13[3]];
    #pragma unroll 1
    for (int ks = 0; ks < 13; ks++) {
      int ksn = (ks < 12) ? ks + 1 : 12;
      int non0 = lneio[rc13[0] + ksn], non1 = lneio[rc13[1] + ksn];
      int non2 = lneio[rc13[2] + ksn], non3 = lneio[rc13[3] + ksn];
      int pf = ksn * 64;
      bf16x8 n00 = *(const bf16x8*)(wA + pf);
      bf16x8 n01 = *(const bf16x8*)(wA + pf + 32);
      bf16x8 n10 = *(const bf16x8*)(wA + 16 * 832 + pf);
      bf16x8 n11 = *(const bf16x8*)(wA + 16 * 832 + pf + 32);
      bf16x8 bv;
      bv = *(const bf16x8*)(zb + no0);
      acc1[0] = MFMA(a00, bv, acc1[0], 0, 0, 0);
      acc1[4] = MFMA(a10, bv, acc1[4], 0, 0, 0);
      bv = *(const bf16x8*)(zb + no1);
      acc1[1] = MFMA(a00, bv, acc1[1], 0, 0, 0);
      acc1[5] = MFMA(a10, bv, acc1[5], 0, 0, 0);
      bv = *(const bf16x8*)(zb + no2);
      acc1[2] = MFMA(a00, bv, acc1[2], 0, 0, 0);
      acc1[6] = MFMA(a10, bv, acc1[6], 0, 0, 0);
      bv = *(const bf16x8*)(zb + no3);
      acc1[3] = MFMA(a00, bv, acc1[3], 0, 0, 0);
      acc1[7] = MFMA(a10, bv, acc1[7], 0, 0, 0);
      bv = *(const bf16x8*)(zb + no0 + 64);
      acc1[0] = MFMA(a01, bv, acc1[0], 0, 0, 0);
      acc1[4] = MFMA(a11, bv, acc1[4], 0, 0, 0);
      bv = *(const bf16x8*)(zb + no1 + 64);
      acc1[1] = MFMA(a01, bv, acc1[1], 0, 0, 0);
      acc1[5] = MFMA(a11, bv, acc1[5], 0, 0, 0);
      bv = *(const bf16x8*)(zb + no2 + 64);
      acc1[2] = MFMA(a01, bv, acc1[2], 0, 0, 0);
      acc1[6] = MFMA(a11, bv, acc1[6], 0, 0, 0);
      bv = *(const bf16x8*)(zb + no3 + 64);
      acc1[3] = MFMA(a01, bv, acc1[3], 0, 0, 0);
      acc1[7] = MFMA(a11, bv, acc1[7], 0, 0, 0);
      a00 = n00; a01 = n01; a10 = n10; a11 = n11;
      no0 = non0; no1 = non1; no2 = non2; no3 = non3;
    }
  }

  // ---- act2(F) -> z2 overwrites z1 (all reads of z1 done at this barrier)
  __syncthreads();
  {
    #pragma unroll
    for (int mt = 0; mt < 2; mt++) {
      int ob = mh * 32 + mt * 16 + quad * 4;
      float a20 = pp[128 + ob],     a21 = pp[128 + ob + 1];
      float a22 = pp[128 + ob + 2], a23 = pp[128 + ob + 3];
      float b20 = pp[192 + ob],     b21 = pp[192 + ob + 1];
      float b22 = pp[192 + ob + 2], b23 = pp[192 + ob + 3];
      #pragma unroll
      for (int nt = 0; nt < 4; nt++) {
        int r = nt * 16 + nl;               // <=63 in-bounds; cols>=60 never read
        f32x4 a = acc1[mt * 4 + nt];
        us4 w;
        w.x = f2bf(fmaxf(fmaf(a[0], a20, b20), 0.f));
        w.y = f2bf(fmaxf(fmaf(a[1], a21, b21), 0.f));
        w.z = f2bf(fmaxf(fmaf(a[2], a22, b22), 0.f));
        w.w = f2bf(fmaxf(fmaf(a[3], a23, b23), 0.f));
        *(us4*)&zbuf[bb][r * ZSTRIDE + ob] = w;
      }
    }
  }
  __syncthreads();

  // ---- stage 2: OUT[128x64] = W23t[128x1664] . [H2(z2); H3(z3)]; wave = 4m x 4n
  f32x4 acc2[16] = {};   // [mt*4+nt]
  {
    const unsigned short* wB = W23t + (mh * 64 + nl) * 1664 + quad * 8;
    #define ROWSTEP (16 * 1664)
    bf16x8 a00 = *(const bf16x8*)(wB),                a01 = *(const bf16x8*)(wB + 32);
    bf16x8 a10 = *(const bf16x8*)(wB + ROWSTEP),      a11 = *(const bf16x8*)(wB + ROWSTEP + 32);
    bf16x8 a20 = *(const bf16x8*)(wB + 2 * ROWSTEP),  a21 = *(const bf16x8*)(wB + 2 * ROWSTEP + 32);
    bf16x8 a30 = *(const bf16x8*)(wB + 3 * ROWSTEP),  a31 = *(const bf16x8*)(wB + 3 * ROWSTEP + 32);
    const char* zlo = (const char*)zbuf[bb] + quad * 16;       // z2
    const char* zhi = (const char*)zbuf[2 + bb] + quad * 16;   // z3
    int no0 = lneio[rc13[0]], no1 = lneio[rc13[1]];
    int no2 = lneio[rc13[2]], no3 = lneio[rc13[3]];
    #pragma unroll 1
    for (int kq = 0; kq < 26; kq++) {
      int kqn = (kq < 25) ? kq + 1 : 25;
      int ksn = (kqn < 13) ? kqn : kqn - 13;
      int non0 = lneio[rc13[0] + ksn], non1 = lneio[rc13[1] + ksn];
      int non2 = lneio[rc13[2] + ksn], non3 = lneio[rc13[3] + ksn];
      int pf = kqn * 64;
      bf16x8 n00 = *(const bf16x8*)(wB + pf),               n01 = *(const bf16x8*)(wB + pf + 32);
      bf16x8 n10 = *(const bf16x8*)(wB + ROWSTEP + pf),     n11 = *(const bf16x8*)(wB + ROWSTEP + pf + 32);
      bf16x8 n20 = *(const bf16x8*)(wB + 2 * ROWSTEP + pf), n21 = *(const bf16x8*)(wB + 2 * ROWSTEP + pf + 32);
      bf16x8 n30 = *(const bf16x8*)(wB + 3 * ROWSTEP + pf), n31 = *(const bf16x8*)(wB + 3 * ROWSTEP + pf + 32);
      const char* zs = (kq < 13) ? zlo : zhi;
      bf16x8 bv;
      bv = *(const bf16x8*)(zs + no0);
      acc2[0]  = MFMA(a00, bv, acc2[0],  0, 0, 0);
      acc2[4]  = MFMA(a10, bv, acc2[4],  0, 0, 0);
      acc2[8]  = MFMA(a20, bv, acc2[8],  0, 0, 0);
      acc2[12] = MFMA(a30, bv, acc2[12], 0, 0, 0);
      bv = *(const bf16x8*)(zs + no1);
      acc2[1]  = MFMA(a00, bv, acc2[1],  0, 0, 0);
      acc2[5]  = MFMA(a10, bv, acc2[5],  0, 0, 0);
      acc2[9]  = MFMA(a20, bv, acc2[9],  0, 0, 0);
      acc2[13] = MFMA(a30, bv, acc2[13], 0, 0, 0);
      bv = *(const bf16x8*)(zs + no2);
      acc2[2]  = MFMA(a00, bv, acc2[2],  0, 0, 0);
      acc2[6]  = MFMA(a10, bv, acc2[6],  0, 0, 0);
      acc2[10] = MFMA(a20, bv, acc2[10], 0, 0, 0);
      acc2[14] = MFMA(a30, bv, acc2[14], 0, 0, 0);
      bv = *(const bf16x8*)(zs + no3);
      acc2[3]  = MFMA(a00, bv, acc2[3],  0, 0, 0);
      acc2[7]  = MFMA(a10, bv, acc2[7],  0, 0, 0);
      acc2[11] = MFMA(a20, bv, acc2[11], 0, 0, 0);
      acc2[15] = MFMA(a30, bv, acc2[15], 0, 0, 0);
      bv = *(const bf16x8*)(zs + no0 + 64);
      acc2[0]  = MFMA(a01, bv, acc2[0],  0, 0, 0);
      acc2[4]  = MFMA(a11, bv, acc2[4],  0, 0, 0);
      acc2[8]  = MFMA(a21, bv, acc2[8],  0, 0, 0);
      acc2[12] = MFMA(a31, bv, acc2[12], 0, 0, 0);
      bv = *(const bf16x8*)(zs + no1 + 64);
      acc2[1]  = MFMA(a01, bv, acc2[1],  0, 0, 0);
      acc2[5]  = MFMA(a11, bv, acc2[5],  0, 0, 0);
      acc2[9]  = MFMA(a21, bv, acc2[9],  0, 0, 0);
      acc2[13] = MFMA(a31, bv, acc2[13], 0, 0, 0);
      bv = *(const bf16x8*)(zs + no2 + 64);
      acc2[2]  = MFMA(a01, bv, acc2[2],  0, 0, 0);
      acc2[6]  = MFMA(a11, bv, acc2[6],  0, 0, 0);
      acc2[10] = MFMA(a21, bv, acc2[10], 0, 0, 0);
      acc2[14] = MFMA(a31, bv, acc2[14], 0, 0, 0);
      bv = *(const bf16x8*)(zs + no3 + 64);
      acc2[3]  = MFMA(a01, bv, acc2[3],  0, 0, 0);
      acc2[7]  = MFMA(a11, bv, acc2[7],  0, 0, 0);
      acc2[11] = MFMA(a21, bv, acc2[11], 0, 0, 0);
      acc2[15] = MFMA(a31, bv, acc2[15], 0, 0, 0);
      a00 = n00; a01 = n01; a10 = n10; a11 = n11;
      a20 = n20; a21 = n21; a30 = n30; a31 = n31;
      no0 = non0; no1 = non1; no2 = non2; no3 = non3;
    }
  }

  // ---- epilogue: out[b][o][r] = acc2 + (c2[o] + c3[o])
  float* outb = out + (batch0 + bb) * (128 * 60);
  #pragma unroll
  for (int mt = 0; mt < 4; mt++) {
    int ob = mh * 64 + mt * 16 + quad * 4;
    float q0 = pcc[ob], q1 = pcc[ob + 1], q2 = pcc[ob + 2], q3 = pcc[ob + 3];
    #pragma unroll
    for (int nt = 0; nt < 4; nt++) {
      int r = nt * 16 + nl;
      if (r < 60) {
        f32x4 a = acc2[mt * 4 + nt];
        outb[(ob + 0) * 60 + r] = a[0] + q0;
        outb[(ob + 1) * 60 + r] = a[1] + q1;
        outb[(ob + 2) * 60 + r] = a[2] + q2;
        outb[(ob + 3) * 60 + r] = a[3] + q3;
      }
    }
  }
}

extern "C" void kernel_launch(void* const* d_in, const int* in_sizes, int n_in,
                              void* d_out, int out_size, void* d_ws, size_t ws_size,
                              hipStream_t stream) {
  const float* x   = (const float*)d_in[0];
  const int*   nei = (const int*)d_in[1];
  const float* g1  = (const float*)d_in[2];
  const float* be1 = (const float*)d_in[3];
  const float* mu1 = (const float*)d_in[4];
  const float* va1 = (const float*)d_in[5];
  const float* W1  = (const float*)d_in[6];
  const float* c1  = (const float*)d_in[7];
  const float* g2  = (const float*)d_in[8];
  const float* be2 = (const float*)d_in[9];
  const float* mu2 = (const float*)d_in[10];
  const float* va2 = (const float*)d_in[11];
  const float* W2  = (const float*)d_in[12];
  const float* c2  = (const float*)d_in[13];
  const float* g3  = (const float*)d_in[14];
  const float* be3 = (const float*)d_in[15];
  const float* mu3 = (const float*)d_in[16];
  const float* va3 = (const float*)d_in[17];
  const float* W3  = (const float*)d_in[18];
  const float* c3  = (const float*)d_in[19];

  // workspace: W1t bf16 [64*832] then W23t bf16 [128*1664]  (~532 KB)
  unsigned short* W1t  = (unsigned short*)d_ws;
  unsigned short* W23t = W1t + 64 * 832;

  prep_w<<<80, 256, 0, stream>>>(W1, W2, W3, W1t, W23t);
  fused_k<<<1024, 256, 0, stream>>>(x, nei, g1, be1, mu1, va1, c1,
                                    g2, be2, mu2, va2, c2,
                                    g3, be3, mu3, va3, c3,
                                    W1t, W23t, (float*)d_out);
}